// Round 10
// baseline (337.778 us; speedup 1.0000x reference)
//
#include <hip/hip_runtime.h>
#include <cstdint>
#include <cstddef>

typedef unsigned short USHORT;
typedef __bf16 bf16x8 __attribute__((ext_vector_type(8)));
typedef float f32x4 __attribute__((ext_vector_type(4)));

__device__ __forceinline__ float b2f(USHORT u) {
    union { unsigned int i; float f; } v; v.i = ((unsigned int)u) << 16; return v.f;
}
__device__ __forceinline__ USHORT f2bf(float f) {
    union { float f; unsigned int i; } v; v.f = f;
    unsigned int u = v.i;
    unsigned int r = (u + 0x7FFFu + ((u >> 16) & 1u)) >> 16;
    return (USHORT)r;
}
__device__ __forceinline__ float fexp2(float x) { return __builtin_amdgcn_exp2f(x); }

__device__ __forceinline__ void gload_lds16(const void* g, void* l) {
    __builtin_amdgcn_global_load_lds(
        (const __attribute__((address_space(1))) void*)(uintptr_t)g,
        (__attribute__((address_space(3))) void*)(uint32_t)(uintptr_t)l,
        16, 0, 0);
}

// ---------------- batched f32 -> bf16 weight conversion (1 launch) ----------
__global__ __launch_bounds__(256)
void f2b_all(const float* __restrict__ Wd, const float* __restrict__ W1,
             const float* __restrict__ W2, const float* __restrict__ Wbc,
             USHORT* __restrict__ WdB, USHORT* __restrict__ W1B,
             USHORT* __restrict__ W2B, USHORT* __restrict__ WbcB)
{
    const int bid = blockIdx.x;
    const float* src; USHORT* dst; int off;
    if (bid < 1024)      { src = Wd;  dst = WdB;  off = bid; }
    else if (bid < 5120) { src = W1;  dst = W1B;  off = bid - 1024; }
    else if (bid < 9216) { src = W2;  dst = W2B;  off = bid - 5120; }
    else                 { src = Wbc; dst = WbcB; off = bid - 9216; }
    const int i = (off * 256 + threadIdx.x) * 4;
    float4 v = *(const float4*)(src + i);
    ushort4 o;
    o.x = f2bf(v.x); o.y = f2bf(v.y); o.z = f2bf(v.z); o.w = f2bf(v.w);
    *(ushort4*)(dst + i) = o;
}

// ---------------- LayerNorm: f32 in -> bf16 out. 1 block/token, 256 thr ----
__global__ __launch_bounds__(256)
void ln_kernel(const float* __restrict__ inp, const float* __restrict__ g,
               const float* __restrict__ bsh, USHORT* __restrict__ out)
{
    const int tid = threadIdx.x;
    const size_t row = blockIdx.x;
    float4 t = ((const float4*)inp)[row * 256 + tid];
    float v[4] = { t.x, t.y, t.z, t.w };
    float s = v[0] + v[1] + v[2] + v[3];
    float sq = v[0]*v[0] + v[1]*v[1] + v[2]*v[2] + v[3]*v[3];
    #pragma unroll
    for (int off = 32; off; off >>= 1) { s += __shfl_down(s, off); sq += __shfl_down(sq, off); }
    __shared__ float red[8];
    const int wv = tid >> 6;
    if ((tid & 63) == 0) { red[wv] = s; red[wv + 4] = sq; }
    __syncthreads();
    const float S  = red[0] + red[1] + red[2] + red[3];
    const float SQ = red[4] + red[5] + red[6] + red[7];
    const float mu = S * (1.0f / 1024.0f);
    const float var = SQ * (1.0f / 1024.0f) - mu * mu;
    const float rs = rsqrtf(var + 1e-5f);
    float4 gv = ((const float4*)g)[tid];
    float4 bv = ((const float4*)bsh)[tid];
    ushort4 o;
    o.x = f2bf((v[0] - mu) * rs * gv.x + bv.x);
    o.y = f2bf((v[1] - mu) * rs * gv.y + bv.y);
    o.z = f2bf((v[2] - mu) * rs * gv.z + bv.z);
    o.w = f2bf((v[3] - mu) * rs * gv.w + bv.w);
    ((ushort4*)out)[row * 256 + tid] = o;
}

// ---------------- GEMM: C(M,N) = A(M,K) @ B(N,K)^T, bf16 MFMA ---------------
// EPI 1: gelu -> bf16 row-major (LDS repack, wave-private slices, NO barriers)
// EPI 3: split-K partial -> raw MFMA-C-layout bf16 dwords, coalesced, no LDS.
//   dword index ((i16*(N/16)+j16)*2+rp)*64 + quad*16+fr ; dword = rows
//   (quad*4+rp*2) low half, (+1) high half, col j16*16+fr. Reduce unscrambles.
// BK=64 two-sub-tile staging; GROUP_M=8 swizzle.
template<int EPI>
__global__ __launch_bounds__(256)
void gemm_bt(const USHORT* __restrict__ A, const USHORT* __restrict__ B,
             const float* __restrict__ bias, void* __restrict__ outp,
             void* __restrict__ outp2, int M, int N, int K, int lda, int ldb)
{
    __shared__ __align__(16) unsigned char smem[32768];
    USHORT* As = (USHORT*)smem;
    USHORT* Bs = (USHORT*)(smem + 8192);
    const int tid = threadIdx.x;
    const int lane = tid & 63;
    const int w = tid >> 6;
    const int wr = w >> 1, wc = w & 1;

    const int nx = gridDim.x, ny = gridDim.y;
    const int pid = blockIdx.y * nx + blockIdx.x;
    const int npg = 8 * nx;
    const int gid = pid / npg;
    const int first = gid * 8;
    const int rem = ny - first;
    const int gsz = (rem < 8) ? rem : 8;
    const int py = first + (pid % npg) % gsz;
    const int px = (pid % npg) / gsz;
    const int tm = py * 128;
    const int tn = px * 128;

    uint32_t* po = nullptr;
    if constexpr (EPI == 3) {
        const int z = blockIdx.z;
        A += (size_t)z * K;
        B += (size_t)z * K;
        USHORT* p16 = ((z < 2) ? (USHORT*)outp : (USHORT*)outp2) + (size_t)(z & 1) * M * N;
        po = (uint32_t*)p16;
    }

    f32x4 acc[4][4];
    #pragma unroll
    for (int i = 0; i < 4; i++)
        #pragma unroll
        for (int j = 0; j < 4; j++) acc[i][j] = (f32x4){0.f, 0.f, 0.f, 0.f};

    const int srow = tid >> 2;
    const int scol = (tid & 3) * 8;
    const USHORT* gA0 = A + (size_t)(tm + srow) * lda + scol;
    const USHORT* gA1 = A + (size_t)(tm + 64 + srow) * lda + scol;
    const USHORT* gB0 = B + (size_t)(tn + srow) * ldb + scol;
    const USHORT* gB1 = B + (size_t)(tn + 64 + srow) * ldb + scol;
    USHORT* lA0 = As + w * 512;
    USHORT* lA1 = As + 2048 + w * 512;
    USHORT* lB0 = Bs + w * 512;
    USHORT* lB1 = Bs + 2048 + w * 512;

    const int fr = lane & 15;
    const int fko = (lane >> 4) * 8;
    const int quad = lane >> 4;

    for (int k0 = 0; k0 < K; k0 += 64) {
        gload_lds16(gA0 + k0, lA0);
        gload_lds16(gA1 + k0, lA1);
        gload_lds16(gB0 + k0, lB0);
        gload_lds16(gB1 + k0, lB1);
        gload_lds16(gA0 + k0 + 32, lA0 + 8192);
        gload_lds16(gA1 + k0 + 32, lA1 + 8192);
        gload_lds16(gB0 + k0 + 32, lB0 + 8192);
        gload_lds16(gB1 + k0 + 32, lB1 + 8192);
        __syncthreads();
        #pragma unroll
        for (int h = 0; h < 2; h++) {
            const USHORT* Ah = As + h * 8192;
            const USHORT* Bh = Bs + h * 8192;
            bf16x8 af[4], bfr[4];
            #pragma unroll
            for (int i = 0; i < 4; i++) {
                af[i]  = *(const bf16x8*)(Ah + (wr * 64 + i * 16 + fr) * 32 + fko);
                bfr[i] = *(const bf16x8*)(Bh + (wc * 64 + i * 16 + fr) * 32 + fko);
            }
            #pragma unroll
            for (int i = 0; i < 4; i++)
                #pragma unroll
                for (int j = 0; j < 4; j++)
                    acc[i][j] = __builtin_amdgcn_mfma_f32_16x16x32_bf16(af[i], bfr[j], acc[i][j], 0, 0, 0);
        }
        __syncthreads();
    }

    if constexpr (EPI == 3) {
        // direct coalesced C-layout partial store: 2 dwords per (i,j) per lane
        const int Nt = N >> 4;
        #pragma unroll
        for (int i = 0; i < 4; i++) {
            const int i16 = (tm >> 4) + wr * 4 + i;
            #pragma unroll
            for (int j = 0; j < 4; j++) {
                const int j16 = (tn >> 4) + wc * 4 + j;
                uint32_t* base = po + ((size_t)(i16 * Nt + j16) * 2) * 64 + lane;
                base[0]  = (uint32_t)f2bf(acc[i][j][0]) | ((uint32_t)f2bf(acc[i][j][1]) << 16);
                base[64] = (uint32_t)f2bf(acc[i][j][2]) | ((uint32_t)f2bf(acc[i][j][3]) << 16);
            }
        }
        return;
    } else {
        // LDS repack epilogue — wave-private slices, no cross-wave barriers
        float* eW = (float*)(smem + (size_t)w * 4352);   // 16 rows x 68 f32
        const int rr = lane >> 5;
        const int cc = lane & 31;
        const int gcolb = tn + wc * 64;
        float2 bvv = *(const float2*)&bias[gcolb + cc * 2];

        #pragma unroll
        for (int i = 0; i < 4; i++) {
            #pragma unroll
            for (int j = 0; j < 4; j++)
                #pragma unroll
                for (int r = 0; r < 4; r++)
                    eW[(quad * 4 + r) * 68 + j * 16 + fr] = acc[i][j][r];
            const int grow0 = tm + wr * 64 + i * 16;
            #pragma unroll
            for (int rp = 0; rp < 8; rp++) {
                const int row = rp * 2 + rr;
                const float2 v = *(const float2*)&eW[row * 68 + cc * 2];
                const size_t gidx = (size_t)(grow0 + row) * N + gcolb + cc * 2;
                const float z0 = v.x + bvv.x, z1 = v.y + bvv.y;
                const float u0 = z0 * (0.7978845608f + 0.035677408f * z0 * z0);
                const float u1 = z1 * (0.7978845608f + 0.035677408f * z1 * z1);
                const float s0 = __builtin_amdgcn_rcpf(1.f + fexp2(2.885390082f * u0));
                const float s1 = __builtin_amdgcn_rcpf(1.f + fexp2(2.885390082f * u1));
                const float g0 = z0 * (1.f - s0), g1 = z1 * (1.f - s1);
                const uint32_t pk = (uint32_t)f2bf(g0) | ((uint32_t)f2bf(g1) << 16);
                *(uint32_t*)((USHORT*)outp + gidx) = pk;
            }
        }
    }
}

// helper: extract bf16 half of a packed dword as f32
__device__ __forceinline__ float exhalf(uint32_t v, int hf) {
    union { unsigned int i; float f; } u;
    u.i = hf ? (v & 0xFFFF0000u) : (v << 16);
    return u.f;
}

// ---------------- delta split-K reduce (C-layout partials): softplus --------
__global__ __launch_bounds__(256)
void delta_reduce(const uint32_t* __restrict__ p, const float* __restrict__ bias,
                  float* __restrict__ out)
{
    const size_t PS = (size_t)4096 * 1024 / 2;   // dwords per partial
    const size_t e0 = ((size_t)blockIdx.x * 256 + threadIdx.x) * 4;
    const int row = (int)(e0 >> 10);
    const int col = (int)(e0 & 1023);
    const int i16 = row >> 4, j16 = col >> 4;
    const int quad = (row >> 2) & 3, rp = (row >> 1) & 1, hf = row & 1;
    const size_t base = (((size_t)(i16 * 64 + j16) * 2 + rp) << 6) + (quad * 16 + (col & 15));
    uint4 a = *(const uint4*)(p + base);
    uint4 b = *(const uint4*)(p + PS + base);
    float4 bv = *(const float4*)(bias + col);
    float z[4] = { exhalf(a.x, hf) + exhalf(b.x, hf) + bv.x,
                   exhalf(a.y, hf) + exhalf(b.y, hf) + bv.y,
                   exhalf(a.z, hf) + exhalf(b.z, hf) + bv.z,
                   exhalf(a.w, hf) + exhalf(b.w, hf) + bv.w };
    float4 o;
    o.x = (z[0] > 20.f) ? z[0] : 0.69314718f * __log2f(1.f + fexp2(z[0] * 1.44269504f));
    o.y = (z[1] > 20.f) ? z[1] : 0.69314718f * __log2f(1.f + fexp2(z[1] * 1.44269504f));
    o.z = (z[2] > 20.f) ? z[2] : 0.69314718f * __log2f(1.f + fexp2(z[2] * 1.44269504f));
    o.w = (z[3] > 20.f) ? z[3] : 0.69314718f * __log2f(1.f + fexp2(z[3] * 1.44269504f));
    *(float4*)(out + e0) = o;
}

// ---------------- FFN2 split-K reduce (C-layout partials) -------------------
__global__ __launch_bounds__(256)
void ffn2_reduce(const uint32_t* __restrict__ p01, const uint32_t* __restrict__ p23,
                 const float* __restrict__ bias, const float* __restrict__ extra,
                 float* __restrict__ out)
{
    const size_t PS = (size_t)4096 * 1024 / 2;   // dwords per partial
    const size_t e0 = ((size_t)blockIdx.x * 256 + threadIdx.x) * 4;
    const int row = (int)(e0 >> 10);
    const int col = (int)(e0 & 1023);
    const int i16 = row >> 4, j16 = col >> 4;
    const int quad = (row >> 2) & 3, rp = (row >> 1) & 1, hf = row & 1;
    const size_t base = (((size_t)(i16 * 64 + j16) * 2 + rp) << 6) + (quad * 16 + (col & 15));
    uint4 a = *(const uint4*)(p01 + base);
    uint4 b = *(const uint4*)(p01 + PS + base);
    uint4 c = *(const uint4*)(p23 + base);
    uint4 d = *(const uint4*)(p23 + PS + base);
    float4 bv = *(const float4*)(bias + col);
    float4 ev = *(const float4*)(extra + e0);
    float4 o;
    o.x = exhalf(a.x,hf)+exhalf(b.x,hf)+exhalf(c.x,hf)+exhalf(d.x,hf) + bv.x + ev.x;
    o.y = exhalf(a.y,hf)+exhalf(b.y,hf)+exhalf(c.y,hf)+exhalf(d.y,hf) + bv.y + ev.y;
    o.z = exhalf(a.z,hf)+exhalf(b.z,hf)+exhalf(c.z,hf)+exhalf(d.z,hf) + bv.z + ev.z;
    o.w = exhalf(a.w,hf)+exhalf(b.w,hf)+exhalf(c.w,hf)+exhalf(d.w,hf) + bv.w + ev.w;
    *(float4*)(out + e0) = o;
}

// ---------------- bc = xn @ Wbc^T + bbc via MFMA: 64 tokens/block ----------
__global__ __launch_bounds__(256)
void bc_mfma(const USHORT* __restrict__ xn, const USHORT* __restrict__ WbcB,
             const float* __restrict__ bbc, float* __restrict__ bc)
{
    __shared__ __align__(16) USHORT As[64 * 32];
    __shared__ __align__(16) USHORT Bs[32 * 32];
    const int tid = threadIdx.x;
    const int lane = tid & 63;
    const int w = tid >> 6;
    const int tok0 = blockIdx.x * 64;

    const int srow = tid >> 2;
    const int scol = (tid & 3) * 8;
    const USHORT* gA = xn + (size_t)(tok0 + srow) * 1024 + scol;
    const USHORT* gB = WbcB + (size_t)srow * 1024 + scol;
    USHORT* lA = As + w * 512;
    USHORT* lB = Bs + w * 512;

    const int fr = lane & 15;
    const int fko = (lane >> 4) * 8;
    const int quad = lane >> 4;

    f32x4 acc[2];
    acc[0] = (f32x4){0.f, 0.f, 0.f, 0.f};
    acc[1] = (f32x4){0.f, 0.f, 0.f, 0.f};

    for (int k0 = 0; k0 < 1024; k0 += 32) {
        gload_lds16(gA + k0, lA);
        if (w < 2) gload_lds16(gB + k0, lB);
        __syncthreads();
        bf16x8 af = *(const bf16x8*)(As + (w * 16 + fr) * 32 + fko);
        bf16x8 b0 = *(const bf16x8*)(Bs + (fr) * 32 + fko);
        bf16x8 b1 = *(const bf16x8*)(Bs + (16 + fr) * 32 + fko);
        acc[0] = __builtin_amdgcn_mfma_f32_16x16x32_bf16(af, b0, acc[0], 0, 0, 0);
        acc[1] = __builtin_amdgcn_mfma_f32_16x16x32_bf16(af, b1, acc[1], 0, 0, 0);
        __syncthreads();
    }

    #pragma unroll
    for (int j = 0; j < 2; j++) {
        const int col = j * 16 + fr;
        const float bv = bbc[col];
        #pragma unroll
        for (int r = 0; r < 4; r++) {
            const int row = tok0 + w * 16 + quad * 4 + r;
            bc[(size_t)row * 32 + col] = acc[j][r] + bv;
        }
    }
}

// ---------------- selective scan v3: chunked parallel, lane=h, n in regs ----
#define SCAN_P 64
#define SCAN_T 32

__global__ __launch_bounds__(256)
void scan_pass1(const USHORT* __restrict__ xn, const float* __restrict__ delta,
                const float* __restrict__ bc, const float* __restrict__ Alog,
                float* __restrict__ sEnd, float* __restrict__ Ptot)
{
    const int tid = threadIdx.x;
    const int h = blockIdx.x * 256 + tid;
    const int b = blockIdx.y;
    const int p = blockIdx.z;
    const size_t tok0 = (size_t)b * 2048 + p * SCAN_T;

    __shared__ __align__(16) float sBC[SCAN_T][32];
    {
        int t = tid >> 3, q = (tid & 7) * 4;
        *(float4*)&sBC[t][q] = *(const float4*)(bc + (tok0 + t) * 32 + q);
    }

    float en[16], s[16], P[16];
    #pragma unroll
    for (int k = 0; k < 4; k++) {
        float4 a = *(const float4*)(Alog + h * 16 + k * 4);
        en[k*4+0] = -__expf(a.x) * 1.44269504f;
        en[k*4+1] = -__expf(a.y) * 1.44269504f;
        en[k*4+2] = -__expf(a.z) * 1.44269504f;
        en[k*4+3] = -__expf(a.w) * 1.44269504f;
    }
    #pragma unroll
    for (int n = 0; n < 16; n++) { s[n] = 0.f; P[n] = 1.f; }
    __syncthreads();

    const float* dp = delta + tok0 * 1024 + h;
    const USHORT* xp = xn + tok0 * 1024 + h;
    float d_c = dp[0];
    USHORT x_c = xp[0];
    for (int t = 0; t < SCAN_T; ++t) {
        const int tn = (t < SCAN_T - 1) ? t + 1 : t;
        float d_n = dp[(size_t)tn * 1024];
        USHORT x_n = xp[(size_t)tn * 1024];
        const float dx = d_c * b2f(x_c);
        #pragma unroll
        for (int k = 0; k < 4; k++) {
            float4 Bv = *(const float4*)&sBC[t][k*4];
            float bb[4] = { Bv.x, Bv.y, Bv.z, Bv.w };
            #pragma unroll
            for (int j = 0; j < 4; j++) {
                const int n = k*4 + j;
                const float dA = fexp2(d_c * en[n]);
                s[n] = fmaf(dA, s[n], dx * bb[j]);
                P[n] *= dA;
            }
        }
        d_c = d_n; x_c = x_n;
    }

    const size_t off = (size_t)p * 32768 + ((size_t)b * 1024 + h) * 16;
    #pragma unroll
    for (int k = 0; k < 4; k++) {
        *(float4*)(sEnd + off + k*4) = (float4){ s[k*4], s[k*4+1], s[k*4+2], s[k*4+3] };
        *(float4*)(Ptot + off + k*4) = (float4){ P[k*4], P[k*4+1], P[k*4+2], P[k*4+3] };
    }
}

__global__ __launch_bounds__(256)
void scan_mid(const float* __restrict__ sEnd, const float* __restrict__ Ptot,
              float* __restrict__ sIn)
{
    const int L = blockIdx.x * 256 + threadIdx.x;
    float s = 0.f;
    #pragma unroll 8
    for (int p = 0; p < SCAN_P; ++p) {
        const size_t off = (size_t)p * 32768 + L;
        sIn[off] = s;
        s = fmaf(Ptot[off], s, sEnd[off]);
    }
}

__global__ __launch_bounds__(256)
void scan_pass2(const float* __restrict__ x, const USHORT* __restrict__ xn,
                const float* __restrict__ delta, const float* __restrict__ bc,
                const float* __restrict__ Alog, const float* __restrict__ Dp,
                const float* __restrict__ sIn, float* __restrict__ ssm)
{
    const int tid = threadIdx.x;
    const int h = blockIdx.x * 256 + tid;
    const int b = blockIdx.y;
    const int p = blockIdx.z;
    const size_t tok0 = (size_t)b * 2048 + p * SCAN_T;

    __shared__ __align__(16) float sBC[SCAN_T][32];
    {
        int t = tid >> 3, q = (tid & 7) * 4;
        *(float4*)&sBC[t][q] = *(const float4*)(bc + (tok0 + t) * 32 + q);
    }

    float en[16], s[16];
    #pragma unroll
    for (int k = 0; k < 4; k++) {
        float4 a = *(const float4*)(Alog + h * 16 + k * 4);
        en[k*4+0] = -__expf(a.x) * 1.44269504f;
        en[k*4+1] = -__expf(a.y) * 1.44269504f;
        en[k*4+2] = -__expf(a.z) * 1.44269504f;
        en[k*4+3] = -__expf(a.w) * 1.44269504f;
    }
    const size_t off = (size_t)p * 32768 + ((size_t)b * 1024 + h) * 16;
    #pragma unroll
    for (int k = 0; k < 4; k++) {
        float4 v = *(const float4*)(sIn + off + k*4);
        s[k*4] = v.x; s[k*4+1] = v.y; s[k*4+2] = v.z; s[k*4+3] = v.w;
    }
    const float Dv = Dp[h];
    __syncthreads();

    const float* dp = delta + tok0 * 1024 + h;
    const USHORT* xp = xn + tok0 * 1024 + h;
    const float* xrp = x + tok0 * 1024 + h;
    float* op = ssm + tok0 * 1024 + h;

    float d_c = dp[0];
    USHORT x_c = xp[0];
    float xr_c = xrp[0];
    for (int t = 0; t < SCAN_T; ++t) {
        const int tn = (t < SCAN_T - 1) ? t + 1 : t;
        float d_n = dp[(size_t)tn * 1024];
        USHORT x_n = xp[(size_t)tn * 1024];
        float xr_n = xrp[(size_t)tn * 1024];
        const float xv = b2f(x_c);
        const float dx = d_c * xv;
        float y = 0.f;
        #pragma unroll
        for (int k = 0; k < 4; k++) {
            float4 Bv = *(const float4*)&sBC[t][k*4];
            float4 Cv = *(const float4*)&sBC[t][16 + k*4];
            float bb[4] = { Bv.x, Bv.y, Bv.z, Bv.w };
            float cc[4] = { Cv.x, Cv.y, Cv.z, Cv.w };
            #pragma unroll
            for (int j = 0; j < 4; j++) {
                const int n = k*4 + j;
                const float dA = fexp2(d_c * en[n]);
                s[n] = fmaf(dA, s[n], dx * bb[j]);
                y = fmaf(cc[j], s[n], y);
            }
        }
        op[(size_t)t * 1024] = xr_c + y + Dv * xv;
        d_c = d_n; x_c = x_n; xr_c = xr_n;
    }
}

extern "C" void kernel_launch(void* const* d_in, const int* in_sizes, int n_in,
                              void* d_out, int out_size, void* d_ws, size_t ws_size,
                              hipStream_t stream)
{
    const float* x    = (const float*)d_in[0];
    const float* ln1g = (const float*)d_in[1];
    const float* ln1b = (const float*)d_in[2];
    const float* Wd   = (const float*)d_in[3];
    const float* bd   = (const float*)d_in[4];
    const float* Wbc  = (const float*)d_in[5];
    const float* bbc  = (const float*)d_in[6];
    const float* Alog = (const float*)d_in[7];
    const float* Dp   = (const float*)d_in[8];
    const float* ln2g = (const float*)d_in[9];
    const float* ln2b = (const float*)d_in[10];
    const float* W1   = (const float*)d_in[11];
    const float* b1   = (const float*)d_in[12];
    const float* W2   = (const float*)d_in[13];
    const float* b2   = (const float*)d_in[14];
    float* out = (float*)d_out;

    char* ws = (char*)d_ws;
    const size_t MB = 1024 * 1024;
    float*  deltaW = (float*)(ws + 0);            // 16 MiB
    float*  ssmW   = (float*)(ws + 16 * MB);      // 16 MiB
    USHORT* xnW    = (USHORT*)(ws + 32 * MB);     //  8 MiB
    USHORT* nrmW   = (USHORT*)(ws + 40 * MB);     //  8 MiB
    USHORT* hffW   = (USHORT*)(ws + 48 * MB);     // 32 MiB
    float*  bcW    = (float*)(ws + 80 * MB);      // 512 KiB
    USHORT* WdB    = (USHORT*)(ws + 81 * MB);     //  2 MiB
    USHORT* W1B    = (USHORT*)(ws + 83 * MB);     //  8 MiB
    USHORT* W2B    = (USHORT*)(ws + 91 * MB);     //  8 MiB
    USHORT* WbcB   = (USHORT*)(ws + 99 * MB);     // 64 KiB
    USHORT* dpart  = (USHORT*)(ws + 48 * MB);     // 16 MiB (aliases hffW)
    float*  sEndW  = (float*)(ws + 48 * MB);
    float*  PtotW  = (float*)(ws + 56 * MB);
    float*  sInW   = (float*)(ws + 64 * MB);
    USHORT* ffn2p01 = (USHORT*)(ws + 0);          // aliases deltaW
    USHORT* ffn2p23 = (USHORT*)(ws + 32 * MB);    // aliases xn/nrm

    // 0. convert all weights f32 -> bf16 (single launch)
    f2b_all<<<9248, 256, 0, stream>>>(Wd, W1, W2, Wbc, WdB, W1B, W2B, WbcB);
    // 1. xn = LN1(x)
    ln_kernel<<<4096, 256, 0, stream>>>(x, ln1g, ln1b, xnW);
    // 2a. delta split-K=2 partial GEMMs (C-layout bf16 partials)
    gemm_bt<3><<<dim3(8, 32, 2), 256, 0, stream>>>(xnW, WdB, nullptr, dpart, nullptr, 4096, 1024, 512, 1024, 1024);
    // 2b. delta = softplus(p0+p1+bd)
    delta_reduce<<<4096, 256, 0, stream>>>((const uint32_t*)dpart, bd, deltaW);
    // 3. bc = xn @ Wbc^T + bbc
    bc_mfma<<<64, 256, 0, stream>>>(xnW, WbcB, bbc, bcW);
    // 4. chunked parallel scan
    scan_pass1<<<dim3(4, 2, SCAN_P), 256, 0, stream>>>(xnW, deltaW, bcW, Alog, sEndW, PtotW);
    scan_mid<<<128, 256, 0, stream>>>(sEndW, PtotW, sInW);
    scan_pass2<<<dim3(4, 2, SCAN_P), 256, 0, stream>>>(x, xnW, deltaW, bcW, Alog, Dp, sInW, ssmW);
    // 5. normed = LN2(ssm_out)
    ln_kernel<<<4096, 256, 0, stream>>>(ssmW, ln2g, ln2b, nrmW);
    // 6. hff = gelu(normed @ W1^T + b1)
    gemm_bt<1><<<dim3(32, 32), 256, 0, stream>>>(nrmW, W1B, b1, hffW, nullptr, 4096, 4096, 1024, 1024, 1024);
    // 7a. FFN2 split-K=4 partial GEMMs (C-layout bf16 partials)
    gemm_bt<3><<<dim3(8, 32, 4), 256, 0, stream>>>(hffW, W2B, nullptr, ffn2p01, ffn2p23, 4096, 1024, 1024, 4096, 4096);
    // 7b. out = sum(partials) + b2 + ssm_out
    ffn2_reduce<<<4096, 256, 0, stream>>>((const uint32_t*)ffn2p01, (const uint32_t*)ffn2p23, b2, ssmW, out);

    (void)in_sizes; (void)n_in; (void)out_size; (void)ws_size;
}